// Round 4
// baseline (402.239 us; speedup 1.0000x reference)
//
#include <hip/hip_runtime.h>

#define WORKER_NUM 2000
#define TASK_NUM   5000
#define EDGE_TYPE  10
#define INPUT_DIM  64

// Output: 2000 * 5000 * 10 = 100,000,000 fp32 (400 MB) -> store-BW-bound.
#define TAU_ELEMS  (TASK_NUM * EDGE_TYPE)       // 50,000
#define TAU4       (TAU_ELEMS / 4)              // 12,500 float4 per worker row

typedef float f32x4 __attribute__((ext_vector_type(4)));  // native vec: legal
                                                          // for nontemporal builtins

// ---------------------------------------------------------------------------
// Prep: blocks [0,500) -> per-worker (base, slope) in log2 space, one wave
// per worker (coalesced row load + shfl_xor reduce).
// blocks [500, 696) -> pack tau (strided slice of inputs) into a dense buffer.
// ---------------------------------------------------------------------------
__global__ __launch_bounds__(256) void prep_kernel(
    const float* __restrict__ inputs,
    const float* __restrict__ W,
    const float* __restrict__ b,
    float2* __restrict__ params,   // [WORKER_NUM] {base=log2(p2), slope=log2(p1)-log2(p2)}
    float* __restrict__ tau)       // [TAU_ELEMS] dense
{
    const int bid = blockIdx.x;
    if (bid < WORKER_NUM / 4) {
        // 4 waves per block, 1 worker per wave
        const int gtid = bid * 256 + (int)threadIdx.x;
        const int w    = gtid >> 6;          // worker index 0..1999
        const int lane = threadIdx.x & 63;
        float v = inputs[w * INPUT_DIM + lane] * W[lane];
        #pragma unroll
        for (int m = 32; m > 0; m >>= 1) v += __shfl_xor(v, m, 64);
        if (lane == 0) {
            float z  = v + b[0];
            float p1 = 1.0f / (1.0f + expf(-z));
            float p2 = (1.0f - p1) / (float)(EDGE_TYPE - 1);
            float l1 = log2f(p1);
            float l2 = log2f(p2);
            params[w] = make_float2(l2, l1 - l2);
        }
    } else {
        const int j = (bid - WORKER_NUM / 4) * 256 + (int)threadIdx.x;
        if (j < TAU_ELEMS) {
            const int t = j / EDGE_TYPE;
            const int e = j - t * EDGE_TYPE;
            tau[j] = inputs[(WORKER_NUM + t) * INPUT_DIM + e];
        }
    }
}

// ---------------------------------------------------------------------------
// Main: out[w][t][e] = exp2(base[w] + tau[t*10+e] * slope[w])
// One worker row per blockIdx.y: params[w] is a wave-uniform scalar load
// (SGPR-resident), no integer division anywhere in the hot loop.
// tau (200 KB) stays L2/L3-resident; output streams via non-temporal stores
// so the 400 MB write never thrashes the 4 MB/XCD L2.
// ---------------------------------------------------------------------------
__global__ __launch_bounds__(256) void decoder_kernel(
    const float2* __restrict__ params,
    const f32x4* __restrict__ tau4,
    f32x4* __restrict__ out4)
{
    const int w = (int)blockIdx.y;               // 0..1999, uniform
    const float2 pw = params[w];                 // scalar load -> SGPRs
    f32x4* __restrict__ orow = out4 + (size_t)w * TAU4;
    const int stride = (int)(gridDim.x * blockDim.x);   // 8*256 = 2048
    for (int i = (int)(blockIdx.x * blockDim.x + threadIdx.x);
         i < TAU4; i += stride) {
        const f32x4 tv = tau4[i];
        f32x4 o;
        o.x = __builtin_amdgcn_exp2f(fmaf(tv.x, pw.y, pw.x));
        o.y = __builtin_amdgcn_exp2f(fmaf(tv.y, pw.y, pw.x));
        o.z = __builtin_amdgcn_exp2f(fmaf(tv.z, pw.y, pw.x));
        o.w = __builtin_amdgcn_exp2f(fmaf(tv.w, pw.y, pw.x));
        __builtin_nontemporal_store(o, &orow[i]);
    }
}

extern "C" void kernel_launch(void* const* d_in, const int* in_sizes, int n_in,
                              void* d_out, int out_size, void* d_ws, size_t ws_size,
                              hipStream_t stream) {
    const float* inputs = (const float*)d_in[0];
    const float* W      = (const float*)d_in[1];
    const float* b      = (const float*)d_in[2];
    float* out          = (float*)d_out;

    // Workspace layout: params (2000 float2, 16 KB slot) | tau (50,000 float)
    float2* params = (float2*)d_ws;
    float*  tau    = (float*)((char*)d_ws + 16384);

    const int prep_blocks = WORKER_NUM / 4 + (TAU_ELEMS + 255) / 256; // 500 + 196
    prep_kernel<<<prep_blocks, 256, 0, stream>>>(inputs, W, b, params, tau);

    decoder_kernel<<<dim3(8, WORKER_NUM), 256, 0, stream>>>(
        params, (const f32x4*)tau, (f32x4*)out);
}